// Round 2
// baseline (332.652 us; speedup 1.0000x reference)
//
#include <hip/hip_runtime.h>
#include <hip/hip_cooperative_groups.h>

namespace cg = cooperative_groups;

// Problem constants (from reference)
#define BATCH 4
#define POINT_NUM 50000
#define NPTS (BATCH * POINT_NUM)   // 200000
#define NVOX 150000
#define FEAT 256

// Persistent cooperative grid: 1024 blocks x 256 threads = 4 blocks/CU,
// 16 waves/CU. launch_bounds(256,4) caps VGPR at 128 (kernel uses far less)
// so co-residency for grid.sync() is guaranteed.
#define NBLOCKS 1024
#define TPB 256
#define NWAVES (NBLOCKS * (TPB / 64))   // 4096 waves

// Phase 1: project ALL voxel rows (sequential 153.6 MB sweep -> stream BW).
//   One wave per row per iteration; 2-row unroll keeps 2 x 1KB loads in
//   flight per wave (32 KB/CU outstanding > the ~10 KB needed to cover
//   ~900cy HBM latency at this kernel's per-CU BW share).
// grid.sync()
// Phase 2: per-point gather of the 2 projected scores (tables are 1.2 MB,
//   L2/LLC-resident after phase 1) -> write straight to out.
__global__ __launch_bounds__(TPB, 4) void fused_coop(
    const float* __restrict__ feat,   // [NVOX, FEAT]
    const int*   __restrict__ idx,    // [NPTS]
    const float* __restrict__ w,      // [2, FEAT]
    const float* __restrict__ bias,   // [2]
    float* __restrict__ s0,           // [NVOX] scratch (workspace)
    float* __restrict__ s1,           // [NVOX] scratch (workspace)
    float* __restrict__ out)          // [2, NPTS]
{
    cg::grid_group grid = cg::this_grid();

    const int tid  = blockIdx.x * TPB + threadIdx.x;
    const int wave = tid >> 6;
    const int lane = threadIdx.x & 63;

    // Weight rows: 2 KB, L1-resident after first touch.
    const float4 w0 = ((const float4*)(w))[lane];
    const float4 w1 = ((const float4*)(w + FEAT))[lane];
    const float b0 = bias[0];
    const float b1 = bias[1];

    // ---- Phase 1: project all voxels ----
    for (int row = wave; row < NVOX; row += 2 * NWAVES) {
        const int row2 = row + NWAVES;
        const bool has2 = (row2 < NVOX);

        // Issue both loads before any compute -> 2 in flight per wave.
        const float4 f1 = ((const float4*)(feat + (size_t)row * FEAT))[lane];
        float4 f2;
        if (has2) f2 = ((const float4*)(feat + (size_t)row2 * FEAT))[lane];

        float a1 = f1.x * w0.x + f1.y * w0.y + f1.z * w0.z + f1.w * w0.w;
        float c1 = f1.x * w1.x + f1.y * w1.y + f1.z * w1.z + f1.w * w1.w;
        float a2 = 0.f, c2 = 0.f;
        if (has2) {
            a2 = f2.x * w0.x + f2.y * w0.y + f2.z * w0.z + f2.w * w0.w;
            c2 = f2.x * w1.x + f2.y * w1.y + f2.z * w1.z + f2.w * w1.w;
        }

        #pragma unroll
        for (int off = 32; off > 0; off >>= 1) {
            a1 += __shfl_down(a1, off, 64);
            c1 += __shfl_down(c1, off, 64);
            a2 += __shfl_down(a2, off, 64);
            c2 += __shfl_down(c2, off, 64);
        }

        if (lane == 0) {
            s0[row] = a1 + b0;
            s1[row] = c1 + b1;
            if (has2) {
                s0[row2] = a2 + b0;
                s1[row2] = c2 + b1;
            }
        }
    }

    // Device-scope visibility of s0/s1 for all blocks.
    grid.sync();

    // ---- Phase 2: gather into out ----
    // 262144 threads >= 200000 points: single trip, coalesced 4B stores.
    for (int p = tid; p < NPTS; p += NBLOCKS * TPB) {
        const int v = idx[p];
        out[p]        = s0[v];   // seal_score_pred
        out[NPTS + p] = s1[v];   // wrench_score_pred
    }
}

extern "C" void kernel_launch(void* const* d_in, const int* in_sizes, int n_in,
                              void* d_out, int out_size, void* d_ws, size_t ws_size,
                              hipStream_t stream) {
    const float* feat = (const float*)d_in[0];
    const int*   idx  = (const int*)d_in[1];
    const float* w    = (const float*)d_in[2];
    const float* bias = (const float*)d_in[3];
    float* out = (float*)d_out;

    float* s0 = (float*)d_ws;          // [NVOX]
    float* s1 = s0 + NVOX;             // [NVOX]  (1.2 MB total)

    void* args[] = { (void*)&feat, (void*)&idx, (void*)&w, (void*)&bias,
                     (void*)&s0, (void*)&s1, (void*)&out };
    hipLaunchCooperativeKernel((void*)fused_coop, dim3(NBLOCKS), dim3(TPB),
                               args, 0, stream);
}

// Round 3
// 223.864 us; speedup vs baseline: 1.4860x; 1.4860x over previous
//
#include <hip/hip_runtime.h>

// Problem constants (from reference)
#define BATCH 4
#define POINT_NUM 50000
#define NPTS (BATCH * POINT_NUM)   // 200000
#define NVOX 150000
#define FEAT 256

// Pass 0: mark referenced voxels. 200K coalesced idx reads, racy byte
// stores (all write 1 -> benign) into a 150KB L2-resident bytemap.
__global__ __launch_bounds__(256) void build_map_kernel(
    const int* __restrict__ idx,          // [NPTS]
    unsigned char* __restrict__ map)      // [NVOX]
{
    const int p = blockIdx.x * blockDim.x + threadIdx.x;
    if (p < NPTS) map[idx[p]] = 1;
}

// Pass 1: project REFERENCED voxels through the 2x256 linear layer.
// One wave (64 lanes) per voxel row: lane l loads float4 at [4l,4l+4),
// computes both partial dots, butterfly-reduces, lane 0 writes 2 scalars.
// Waves -> rows sequentially, so the read stream is sequential with 1KB
// holes at unreferenced rows (~26%): near-stream DRAM efficiency while
// saving ~40MB of the 153.6MB sweep.
// Unmarked rows keep garbage in s0/s1 -- never read by the gather.
__global__ __launch_bounds__(256) void project_kernel(
    const float* __restrict__ feat,       // [NVOX, FEAT]
    const float* __restrict__ w,          // [2, FEAT]
    const float* __restrict__ bias,       // [2]
    const unsigned char* __restrict__ map,// [NVOX]
    float* __restrict__ s0,               // [NVOX] scratch
    float* __restrict__ s1)               // [NVOX] scratch
{
    const int wave = (blockIdx.x * blockDim.x + threadIdx.x) >> 6;
    const int lane = threadIdx.x & 63;
    if (wave >= NVOX) return;

    // All 64 lanes read the same byte -> broadcast; uniform branch.
    if (!map[wave]) return;

    const float4 w0 = ((const float4*)(w))[lane];
    const float4 w1 = ((const float4*)(w + FEAT))[lane];
    const float4 f  = ((const float4*)(feat + (size_t)wave * FEAT))[lane];

    float a = f.x * w0.x + f.y * w0.y + f.z * w0.z + f.w * w0.w;
    float b = f.x * w1.x + f.y * w1.y + f.z * w1.z + f.w * w1.w;

    #pragma unroll
    for (int off = 32; off > 0; off >>= 1) {
        a += __shfl_down(a, off, 64);
        b += __shfl_down(b, off, 64);
    }

    if (lane == 0) {
        s0[wave] = a + bias[0];
        s1[wave] = b + bias[1];
    }
}

// Pass 2: per-point gather of the 2 projected scores. Score tables are
// 600 KB each -> L2-resident; random 4B reads are cheap here.
__global__ __launch_bounds__(256) void gather_kernel(
    const int* __restrict__ idx,          // [NPTS]
    const float* __restrict__ s0,
    const float* __restrict__ s1,
    float* __restrict__ out)              // [2, NPTS]
{
    const int p = blockIdx.x * blockDim.x + threadIdx.x;
    if (p >= NPTS) return;
    const int v = idx[p];
    out[p]        = s0[v];   // seal_score_pred
    out[NPTS + p] = s1[v];   // wrench_score_pred
}

extern "C" void kernel_launch(void* const* d_in, const int* in_sizes, int n_in,
                              void* d_out, int out_size, void* d_ws, size_t ws_size,
                              hipStream_t stream) {
    const float* feat = (const float*)d_in[0];
    const int*   idx  = (const int*)d_in[1];
    const float* w    = (const float*)d_in[2];
    const float* bias = (const float*)d_in[3];
    float* out = (float*)d_out;

    // Workspace layout: s0 [NVOX floats] | s1 [NVOX floats] | map [NVOX bytes]
    float* s0 = (float*)d_ws;
    float* s1 = s0 + NVOX;
    unsigned char* map = (unsigned char*)(s1 + NVOX);

    // Zero the bytemap (150 KB). Async fill on the stream -> capturable.
    hipMemsetAsync(map, 0, NVOX, stream);

    const int blocks0 = (NPTS + 255) / 256;
    build_map_kernel<<<blocks0, 256, 0, stream>>>(idx, map);

    // 150000 waves, 4 waves per 256-thread block
    const int blocks1 = (NVOX * 64 + 255) / 256;
    project_kernel<<<blocks1, 256, 0, stream>>>(feat, w, bias, map, s0, s1);

    const int blocks2 = (NPTS + 255) / 256;
    gather_kernel<<<blocks2, 256, 0, stream>>>(idx, s0, s1, out);
}

// Round 4
// 215.407 us; speedup vs baseline: 1.5443x; 1.0393x over previous
//
#include <hip/hip_runtime.h>

// Problem constants (from reference)
#define BATCH 4
#define POINT_NUM 50000
#define NPTS (BATCH * POINT_NUM)   // 200000
#define NVOX 150000
#define FEAT 256

// Pass 1: project ALL voxels through the 2x256 linear layer.
// One wave (64 lanes) per voxel row: lane l loads float4 at [4l,4l+4),
// computes both partial dots, butterfly-reduces, lane 0 writes 2 scalars.
// Reads are fully sequential (consecutive waves -> consecutive rows), so
// this streams at HBM BW (~6.7 TB/s measured = the achievable ceiling).
//
// Session verdict (rounds 0-3): this structure is optimal.
//  - fused per-point gather of feature rows: +23 us (random 1KB rows
//    stream at <half sequential BW, LLC absorption notwithstanding)
//  - cooperative persistent grid: +117 us (loop-carried reduce serializes
//    loads; wave-churn gives far more MLP)
//  - bytemap-sparsified sweep (skip ~26% unreferenced rows): +8 us
//    (1KB holes don't shorten DRAM time; extra dispatches cost more)
// Remaining headline time is ~182 us of unconditional harness workspace
// poison fills + ~23 us project at stream roofline + ~3 us gather.
__global__ __launch_bounds__(256) void project_kernel(
    const float* __restrict__ feat,   // [NVOX, FEAT]
    const float* __restrict__ w,      // [2, FEAT]
    const float* __restrict__ bias,   // [2]
    float* __restrict__ s0,           // [NVOX] scratch
    float* __restrict__ s1)           // [NVOX] scratch
{
    const int wave = (blockIdx.x * blockDim.x + threadIdx.x) >> 6;
    const int lane = threadIdx.x & 63;
    if (wave >= NVOX) return;

    const float4 w0 = ((const float4*)(w))[lane];
    const float4 w1 = ((const float4*)(w + FEAT))[lane];
    const float4 f  = ((const float4*)(feat + (size_t)wave * FEAT))[lane];

    float a = f.x * w0.x + f.y * w0.y + f.z * w0.z + f.w * w0.w;
    float b = f.x * w1.x + f.y * w1.y + f.z * w1.z + f.w * w1.w;

    #pragma unroll
    for (int off = 32; off > 0; off >>= 1) {
        a += __shfl_down(a, off, 64);
        b += __shfl_down(b, off, 64);
    }

    if (lane == 0) {
        s0[wave] = a + bias[0];
        s1[wave] = b + bias[1];
    }
}

// Pass 2: per-point gather of the 2 projected scores. The score tables are
// 600 KB each -> L2-resident; random 4B reads are cheap here.
__global__ __launch_bounds__(256) void gather_kernel(
    const int* __restrict__ idx,      // [NPTS]
    const float* __restrict__ s0,
    const float* __restrict__ s1,
    float* __restrict__ out)          // [2, NPTS]
{
    const int p = blockIdx.x * blockDim.x + threadIdx.x;
    if (p >= NPTS) return;
    const int v = idx[p];
    out[p]        = s0[v];   // seal_score_pred
    out[NPTS + p] = s1[v];   // wrench_score_pred
}

extern "C" void kernel_launch(void* const* d_in, const int* in_sizes, int n_in,
                              void* d_out, int out_size, void* d_ws, size_t ws_size,
                              hipStream_t stream) {
    const float* feat = (const float*)d_in[0];
    const int*   idx  = (const int*)d_in[1];
    const float* w    = (const float*)d_in[2];
    const float* bias = (const float*)d_in[3];
    float* out = (float*)d_out;

    float* s0 = (float*)d_ws;          // [NVOX]
    float* s1 = s0 + NVOX;             // [NVOX]  (1.2 MB total, ws is plenty)

    // 150000 waves, 4 waves per 256-thread block
    const int blocks1 = (NVOX * 64 + 255) / 256;
    project_kernel<<<blocks1, 256, 0, stream>>>(feat, w, bias, s0, s1);

    const int blocks2 = (NPTS + 255) / 256;
    gather_kernel<<<blocks2, 256, 0, stream>>>(idx, s0, s1, out);
}